// Round 1
// baseline (757.331 us; speedup 1.0000x reference)
//
#include <hip/hip_runtime.h>
#include <stdint.h>
#include <stddef.h>

#define B_N    16384
#define NCLS_N 1000
#define C_N    1280

// workspace layout (bytes). Required ws_size >= ~52.8 MB.
#define ACC_OFF    0ULL
#define COLSUM_OFF 128ULL
#define FBT_OFF    8192ULL                         // bf16 [1280][16384]
#define WB_OFF     41951232ULL                     // bf16 [1024][1280] (rows >=1000 zero)
#define G_OFF      44572672ULL                     // fp32 [1280][1280]
#define H_OFF      51126272ULL                     // fp32 [1024][1024]

enum { A_NLL = 0, A_KL = 1, A_L1 = 2, A_L2SQ = 3, A_SUMSQF = 4, A_FMU2 = 5, A_GFRO = 6, A_HFRO = 7 };

typedef short s16x8 __attribute__((ext_vector_type(8)));
typedef short s16x4 __attribute__((ext_vector_type(4)));
typedef float f32x4 __attribute__((ext_vector_type(4)));

__device__ __forceinline__ unsigned short f2bf(float f) {
    union { float f; unsigned int u; } v; v.f = f;
    unsigned int u = v.u;
    u += 0x7fffu + ((u >> 16) & 1u);   // RNE
    return (unsigned short)(u >> 16);
}

__device__ __forceinline__ float wave_red(float v) {
#pragma unroll
    for (int o = 32; o; o >>= 1) v += __shfl_down(v, o, 64);
    return v;
}

// ---------------- NLL gather ----------------
__global__ __launch_bounds__(256) void nll_kernel(const float* __restrict__ lp,
                                                  const int* __restrict__ tgt,
                                                  float* __restrict__ acc) {
    int b = blockIdx.x * 256 + threadIdx.x;
    int t = tgt[b];
    float v = lp[(size_t)b * NCLS_N + t];
    v = wave_red(v);
    __shared__ float sm[4];
    int wid = threadIdx.x >> 6, lane = threadIdx.x & 63;
    if (lane == 0) sm[wid] = v;
    __syncthreads();
    if (threadIdx.x == 0) atomicAdd(&acc[A_NLL], sm[0] + sm[1] + sm[2] + sm[3]);
}

// ---------------- weights: cast to bf16 (padded to 1024 rows) + L1 + L2sq ----------------
__global__ __launch_bounds__(256) void wpass_kernel(const float* __restrict__ W,
                                                    short* __restrict__ Wb,
                                                    float* __restrict__ acc) {
    int gid = blockIdx.x * 256 + threadIdx.x;   // 0 .. 1024*1280/4 - 1
    int e = gid * 4;
    int row = e / C_N;
    int col = e - row * C_N;
    float l1 = 0.f, l2 = 0.f;
    s16x4 pk = { 0, 0, 0, 0 };
    if (row < NCLS_N) {
        float4 w = *(const float4*)(W + (size_t)row * C_N + col);
        l1 = fabsf(w.x) + fabsf(w.y) + fabsf(w.z) + fabsf(w.w);
        l2 = w.x * w.x + w.y * w.y + w.z * w.z + w.w * w.w;
        pk[0] = (short)f2bf(w.x); pk[1] = (short)f2bf(w.y);
        pk[2] = (short)f2bf(w.z); pk[3] = (short)f2bf(w.w);
    }
    *(s16x4*)(Wb + (size_t)row * C_N + col) = pk;

    l1 = wave_red(l1);
    l2 = wave_red(l2);
    __shared__ float sm[4][2];
    int wid = threadIdx.x >> 6, lane = threadIdx.x & 63;
    if (lane == 0) { sm[wid][0] = l1; sm[wid][1] = l2; }
    __syncthreads();
    if (threadIdx.x == 0) {
        atomicAdd(&acc[A_L1],   sm[0][0] + sm[1][0] + sm[2][0] + sm[3][0]);
        atomicAdd(&acc[A_L2SQ], sm[0][1] + sm[1][1] + sm[2][1] + sm[3][1]);
    }
}

// ---------------- features: transpose to bf16 Fbt[C][B] + column sums + sum of squares ----------------
__global__ __launch_bounds__(256) void fpass_kernel(const float* __restrict__ F,
                                                    short* __restrict__ Fbt,
                                                    float* __restrict__ colsum,
                                                    float* __restrict__ acc) {
    int c = blockIdx.x * 256 + threadIdx.x;   // 0..1279
    int kbase = blockIdx.y * 128;
    float cs = 0.f, sq = 0.f;
    for (int it = 0; it < 16; it++) {
        int k = kbase + it * 8;
        float v[8];
#pragma unroll
        for (int r = 0; r < 8; r++) v[r] = F[(size_t)(k + r) * C_N + c];
        s16x8 pk;
#pragma unroll
        for (int r = 0; r < 8; r++) {
            cs += v[r];
            sq += v[r] * v[r];
            pk[r] = (short)f2bf(v[r]);
        }
        *(s16x8*)(Fbt + (size_t)c * B_N + k) = pk;
    }
    atomicAdd(&colsum[c], cs);
    sq = wave_red(sq);
    __shared__ float sm[4];
    int wid = threadIdx.x >> 6, lane = threadIdx.x & 63;
    if (lane == 0) sm[wid] = sq;
    __syncthreads();
    if (threadIdx.x == 0) atomicAdd(&acc[A_SUMSQF], sm[0] + sm[1] + sm[2] + sm[3]);
}

// ---------------- per-row: KL term + ||F mu||^2 term ----------------
// kl_row = C * (sum e^f * f)/(sum e^f) - sum f     (log s cancels analytically; f~N(0,1) so no overflow)
__global__ __launch_bounds__(320) void klpass_kernel(const float* __restrict__ F,
                                                     const float* __restrict__ colsum,
                                                     float* __restrict__ acc) {
    int b = blockIdx.x;
    int t4 = threadIdx.x * 4;
    float4 f = *(const float4*)(F + (size_t)b * C_N + t4);
    float4 m = *(const float4*)(colsum + t4);
    float e0 = __expf(f.x), e1 = __expf(f.y), e2 = __expf(f.z), e3 = __expf(f.w);
    float s  = e0 + e1 + e2 + e3;
    float tt = e0 * f.x + e1 * f.y + e2 * f.z + e3 * f.w;
    float sf = f.x + f.y + f.z + f.w;
    float dp = f.x * m.x + f.y * m.y + f.z * m.z + f.w * m.w;

    s = wave_red(s); tt = wave_red(tt); sf = wave_red(sf); dp = wave_red(dp);
    __shared__ float sm[5][4];
    int wid = threadIdx.x >> 6, lane = threadIdx.x & 63;
    if (lane == 0) { sm[wid][0] = s; sm[wid][1] = tt; sm[wid][2] = sf; sm[wid][3] = dp; }
    __syncthreads();
    if (threadIdx.x == 0) {
        float S = 0, T = 0, SF = 0, DP = 0;
#pragma unroll
        for (int w = 0; w < 5; w++) { S += sm[w][0]; T += sm[w][1]; SF += sm[w][2]; DP += sm[w][3]; }
        float kl = (float)C_N * (T / S) - SF;
        float dot = DP * (1.f / (float)B_N);   // F mu for this row (mu = colsum/B)
        atomicAdd(&acc[A_KL], kl);
        atomicAdd(&acc[A_FMU2], dot * dot);
    }
}

// ---------------- bf16 Gram: S += X X^T over triangular tiles, K-split, atomic epilogue ----------------
// X: [Mp][K] bf16 row-major.  128x128 tile per block, 4 waves (2x2 of 64x64), BK=32, 16x16x32 MFMA.
__global__ __launch_bounds__(256) void gram_kernel(const short* __restrict__ X,
                                                   float* __restrict__ S,
                                                   int Mp, int K, int T, int ntri, int chunkK) {
    __shared__ __align__(16) short At[128 * 32];
    __shared__ __align__(16) short Bt[128 * 32];
    int tid = threadIdx.x;
    int tile = blockIdx.x % ntri;
    int kc   = blockIdx.x / ntri;
    int bi = 0, rem = tile;
    while (rem >= T - bi) { rem -= T - bi; bi++; }
    int bj = bi + rem;
    int i0 = bi * 128, j0 = bj * 128;
    int k0 = kc * chunkK;
    bool same = (bi == bj);

    int wave = tid >> 6, lane = tid & 63;
    int wm = wave >> 1, wn = wave & 1;
    int quad = lane >> 4, l16 = lane & 15;

    f32x4 acc[4][4];
#pragma unroll
    for (int i = 0; i < 4; i++)
#pragma unroll
        for (int j = 0; j < 4; j++) acc[i][j] = { 0.f, 0.f, 0.f, 0.f };

    for (int kk = 0; kk < chunkK; kk += 32) {
        int kcur = k0 + kk;
#pragma unroll
        for (int it = 0; it < 2; it++) {   // stage A tile (128x32), 16B per lane, wave-uniform base + lane*16
            int g = it * 256 + tid;
            int row = g >> 2, koff = (g & 3) * 8;
            const short* gp = X + (size_t)(i0 + row) * K + kcur + koff;
            __builtin_amdgcn_global_load_lds((const __attribute__((address_space(1))) unsigned int*)gp,
                                             (__attribute__((address_space(3))) unsigned int*)(At + g * 8),
                                             16, 0, 0);
        }
        if (!same) {
#pragma unroll
            for (int it = 0; it < 2; it++) {
                int g = it * 256 + tid;
                int row = g >> 2, koff = (g & 3) * 8;
                const short* gp = X + (size_t)(j0 + row) * K + kcur + koff;
                __builtin_amdgcn_global_load_lds((const __attribute__((address_space(1))) unsigned int*)gp,
                                                 (__attribute__((address_space(3))) unsigned int*)(Bt + g * 8),
                                                 16, 0, 0);
            }
        }
        __syncthreads();
        const short* Bsrc = same ? At : Bt;
        s16x8 af[4], bf[4];
#pragma unroll
        for (int f = 0; f < 4; f++) {
            int mrow = wm * 64 + f * 16 + l16;
            af[f] = *(const s16x8*)(At + mrow * 32 + quad * 8);
            int nrow = wn * 64 + f * 16 + l16;
            bf[f] = *(const s16x8*)(Bsrc + nrow * 32 + quad * 8);
        }
#pragma unroll
        for (int i = 0; i < 4; i++)
#pragma unroll
            for (int j = 0; j < 4; j++)
                acc[i][j] = __builtin_amdgcn_mfma_f32_16x16x32_bf16(af[i], bf[j], acc[i][j], 0, 0, 0);
        __syncthreads();
    }

#pragma unroll
    for (int i = 0; i < 4; i++)
#pragma unroll
        for (int j = 0; j < 4; j++)
#pragma unroll
            for (int r = 0; r < 4; r++) {
                int grow = i0 + wm * 64 + i * 16 + quad * 4 + r;
                int gcol = j0 + wn * 64 + j * 16 + l16;
                atomicAdd(&S[(size_t)grow * Mp + gcol], acc[i][j][r]);
            }
}

// ---------------- Frobenius^2 over computed triangular tiles (off-diag weighted 2x) ----------------
__global__ __launch_bounds__(256) void fro_reduce_kernel(const float* __restrict__ S,
                                                         int Mp, int T, float* __restrict__ slot) {
    int tile = blockIdx.x;
    int bi = 0, rem = tile;
    while (rem >= T - bi) { rem -= T - bi; bi++; }
    int bj = bi + rem;
    size_t base = (size_t)bi * 128 * Mp + (size_t)bj * 128;
    float sum = 0.f;
    for (int l = threadIdx.x * 4; l < 128 * 128; l += 1024) {
        int row = l >> 7, col = l & 127;
        float4 v = *(const float4*)(S + base + (size_t)row * Mp + col);
        sum += v.x * v.x + v.y * v.y + v.z * v.z + v.w * v.w;
    }
    sum = wave_red(sum);
    __shared__ float sm[4];
    int wid = threadIdx.x >> 6, lane = threadIdx.x & 63;
    if (lane == 0) sm[wid] = sum;
    __syncthreads();
    if (threadIdx.x == 0) {
        float w = (bi == bj) ? 1.f : 2.f;
        atomicAdd(slot, w * (sm[0] + sm[1] + sm[2] + sm[3]));
    }
}

// ---------------- final combine ----------------
__global__ __launch_bounds__(256) void final_kernel(const float* __restrict__ acc,
                                                    const float* __restrict__ colsum,
                                                    float* __restrict__ out) {
    float s = 0.f;
    for (int c = threadIdx.x; c < C_N; c += 256) { float v = colsum[c]; s += v * v; }
    s = wave_red(s);
    __shared__ float sm[4];
    int wid = threadIdx.x >> 6, lane = threadIdx.x & 63;
    if (lane == 0) sm[wid] = s;
    __syncthreads();
    if (threadIdx.x == 0) {
        double musq_raw = (double)(sm[0] + sm[1] + sm[2] + sm[3]);   // sum colsum^2 = B^2 * ||mu||^2
        double Bd = (double)B_N;
        double nll = -((double)acc[A_NLL] / Bd);
        double kl  = (double)acc[A_KL] / Bd;
        double trG = (double)acc[A_SUMSQF];
        double musq = musq_raw / (Bd * Bd);
        double cov = (double)acc[A_GFRO] / (Bd * Bd)
                   - (2.0 / Bd) * (double)acc[A_FMU2]
                   + musq * musq
                   - 2.0 * (trG / Bd - musq)
                   + (double)C_N;
        double ortho = (double)acc[A_HFRO] - 2.0 * (double)acc[A_L2SQ] + (double)NCLS_N;
        double loss = 1.0 * nll + 0.2 * kl + 0.2 * cov + 0.1 * ortho
                    + 0.1 * (double)acc[A_L1] + 0.1 * sqrt((double)acc[A_L2SQ]);
        out[0] = (float)loss;
    }
}

extern "C" void kernel_launch(void* const* d_in, const int* in_sizes, int n_in,
                              void* d_out, int out_size, void* d_ws, size_t ws_size,
                              hipStream_t stream) {
    (void)in_sizes; (void)n_in; (void)out_size; (void)ws_size;
    const float* output_lp = (const float*)d_in[0];
    const int*   target    = (const int*)d_in[1];
    const float* W         = (const float*)d_in[2];
    const float* F         = (const float*)d_in[3];

    char*  ws     = (char*)d_ws;
    float* acc    = (float*)(ws + ACC_OFF);
    float* colsum = (float*)(ws + COLSUM_OFF);
    short* Fbt    = (short*)(ws + FBT_OFF);
    short* Wb     = (short*)(ws + WB_OFF);
    float* G      = (float*)(ws + G_OFF);
    float* H      = (float*)(ws + H_OFF);

    // zero accumulators + atomic targets (ws is poisoned 0xAA before every launch)
    hipMemsetAsync(ws, 0, 8192, stream);
    hipMemsetAsync(G, 0, (size_t)C_N * C_N * 4, stream);
    hipMemsetAsync(H, 0, (size_t)1024 * 1024 * 4, stream);

    nll_kernel<<<B_N / 256, 256, 0, stream>>>(output_lp, target, acc);
    wpass_kernel<<<(1024 * C_N / 4) / 256, 256, 0, stream>>>(W, Wb, acc);
    fpass_kernel<<<dim3(C_N / 256, B_N / 128), 256, 0, stream>>>(F, Fbt, colsum, acc);
    klpass_kernel<<<B_N, 320, 0, stream>>>(F, colsum, acc);

    // G = Fbt Fbt^T : Mp=1280, K=16384, T=10, ntri=55, ksplit=8 (chunk 2048) -> 440 blocks
    gram_kernel<<<55 * 8, 256, 0, stream>>>(Fbt, G, C_N, B_N, 10, 55, 2048);
    // H = Wb Wb^T : Mp=1024, K=1280, T=8, ntri=36, ksplit=4 (chunk 320) -> 144 blocks
    gram_kernel<<<36 * 4, 256, 0, stream>>>(Wb, H, 1024, C_N, 8, 36, 320);

    fro_reduce_kernel<<<55, 256, 0, stream>>>(G, C_N, 10, acc + A_GFRO);
    fro_reduce_kernel<<<36, 256, 0, stream>>>(H, 1024, 8, acc + A_HFRO);

    final_kernel<<<1, 256, 0, stream>>>(acc, colsum, (float*)d_out);
}

// Round 2
// 377.228 us; speedup vs baseline: 2.0076x; 2.0076x over previous
//
#include <hip/hip_runtime.h>
#include <stdint.h>
#include <stddef.h>

#define B_N    16384
#define NCLS_N 1000
#define C_N    1280

// workspace layout (bytes). Required ws_size >= ~52.8 MB.
#define ACC_OFF    0ULL
#define COLSUM_OFF 128ULL
#define FBT_OFF    8192ULL                         // bf16 [1280][16384]
#define WB_OFF     41951232ULL                     // bf16 [1024][1280] (rows >=1000 zero)
#define G_OFF      44572672ULL                     // fp32 [1280][1280]
#define H_OFF      51126272ULL                     // fp32 [1024][1024]

enum { A_NLL = 0, A_KL = 1, A_L1 = 2, A_L2SQ = 3, A_SUMSQF = 4, A_FMU2 = 5, A_GFRO = 6, A_HFRO = 7 };

typedef short s16x8 __attribute__((ext_vector_type(8)));
typedef short s16x4 __attribute__((ext_vector_type(4)));
typedef float f32x4 __attribute__((ext_vector_type(4)));

__device__ __forceinline__ unsigned short f2bf(float f) {
    union { float f; unsigned int u; } v; v.f = f;
    unsigned int u = v.u;
    u += 0x7fffu + ((u >> 16) & 1u);   // RNE
    return (unsigned short)(u >> 16);
}

__device__ __forceinline__ float wave_red(float v) {
#pragma unroll
    for (int o = 32; o; o >>= 1) v += __shfl_down(v, o, 64);
    return v;
}

// ---------------- NLL gather ----------------
__global__ __launch_bounds__(256) void nll_kernel(const float* __restrict__ lp,
                                                  const int* __restrict__ tgt,
                                                  float* __restrict__ acc) {
    int b = blockIdx.x * 256 + threadIdx.x;
    int t = tgt[b];
    float v = lp[(size_t)b * NCLS_N + t];
    v = wave_red(v);
    __shared__ float sm[4];
    int wid = threadIdx.x >> 6, lane = threadIdx.x & 63;
    if (lane == 0) sm[wid] = v;
    __syncthreads();
    if (threadIdx.x == 0) atomicAdd(&acc[A_NLL], sm[0] + sm[1] + sm[2] + sm[3]);
}

// ---------------- weights: cast to bf16 (padded to 1024 rows) + L1 + L2sq ----------------
__global__ __launch_bounds__(256) void wpass_kernel(const float* __restrict__ W,
                                                    short* __restrict__ Wb,
                                                    float* __restrict__ acc) {
    int gid = blockIdx.x * 256 + threadIdx.x;   // 0 .. 1024*1280/4 - 1
    int e = gid * 4;
    int row = e / C_N;
    int col = e - row * C_N;
    float l1 = 0.f, l2 = 0.f;
    s16x4 pk = { 0, 0, 0, 0 };
    if (row < NCLS_N) {
        float4 w = *(const float4*)(W + (size_t)row * C_N + col);
        l1 = fabsf(w.x) + fabsf(w.y) + fabsf(w.z) + fabsf(w.w);
        l2 = w.x * w.x + w.y * w.y + w.z * w.z + w.w * w.w;
        pk[0] = (short)f2bf(w.x); pk[1] = (short)f2bf(w.y);
        pk[2] = (short)f2bf(w.z); pk[3] = (short)f2bf(w.w);
    }
    *(s16x4*)(Wb + (size_t)row * C_N + col) = pk;

    l1 = wave_red(l1);
    l2 = wave_red(l2);
    __shared__ float sm[4][2];
    int wid = threadIdx.x >> 6, lane = threadIdx.x & 63;
    if (lane == 0) { sm[wid][0] = l1; sm[wid][1] = l2; }
    __syncthreads();
    if (threadIdx.x == 0) {
        atomicAdd(&acc[A_L1],   sm[0][0] + sm[1][0] + sm[2][0] + sm[3][0]);
        atomicAdd(&acc[A_L2SQ], sm[0][1] + sm[1][1] + sm[2][1] + sm[3][1]);
    }
}

// ---------------- features: transpose to bf16 Fbt[C][B] + column sums + sum of squares ----------------
__global__ __launch_bounds__(256) void fpass_kernel(const float* __restrict__ F,
                                                    short* __restrict__ Fbt,
                                                    float* __restrict__ colsum,
                                                    float* __restrict__ acc) {
    int c = blockIdx.x * 256 + threadIdx.x;   // 0..1279
    int kbase = blockIdx.y * 128;
    float cs = 0.f, sq = 0.f;
    for (int it = 0; it < 16; it++) {
        int k = kbase + it * 8;
        float v[8];
#pragma unroll
        for (int r = 0; r < 8; r++) v[r] = F[(size_t)(k + r) * C_N + c];
        s16x8 pk;
#pragma unroll
        for (int r = 0; r < 8; r++) {
            cs += v[r];
            sq += v[r] * v[r];
            pk[r] = (short)f2bf(v[r]);
        }
        *(s16x8*)(Fbt + (size_t)c * B_N + k) = pk;
    }
    atomicAdd(&colsum[c], cs);
    sq = wave_red(sq);
    __shared__ float sm[4];
    int wid = threadIdx.x >> 6, lane = threadIdx.x & 63;
    if (lane == 0) sm[wid] = sq;
    __syncthreads();
    if (threadIdx.x == 0) atomicAdd(&acc[A_SUMSQF], sm[0] + sm[1] + sm[2] + sm[3]);
}

// ---------------- per-row: KL term + ||F mu||^2 term ----------------
// kl_row = C * (sum e^f * f)/(sum e^f) - sum f     (log s cancels analytically)
// One WAVE per row: lane l handles float4 indices l + 64*i, i=0..4 (1280/4 = 320 float4).
// Local accumulation across rows; ONE atomicAdd per block per quantity (was: per row -> 418us of
// same-address atomic serialization at 1.3% HBM).
__global__ __launch_bounds__(256) void klpass_kernel(const float* __restrict__ F,
                                                     const float* __restrict__ colsum,
                                                     float* __restrict__ acc) {
    int wid = threadIdx.x >> 6, lane = threadIdx.x & 63;
    int gwave = blockIdx.x * 4 + wid;            // 0..4095
    const float4* M = (const float4*)colsum;

    float kl_acc = 0.f, fmu_acc = 0.f;
    for (int b = gwave; b < B_N; b += 4096) {
        const float4* Fr = (const float4*)(F + (size_t)b * C_N);
        float s = 0.f, tt = 0.f, sf = 0.f, dp = 0.f;
#pragma unroll
        for (int i = 0; i < 5; i++) {
            float4 f = Fr[lane + 64 * i];
            float4 m = M[lane + 64 * i];
            float e0 = __expf(f.x), e1 = __expf(f.y), e2 = __expf(f.z), e3 = __expf(f.w);
            s  += e0 + e1 + e2 + e3;
            tt += e0 * f.x + e1 * f.y + e2 * f.z + e3 * f.w;
            sf += f.x + f.y + f.z + f.w;
            dp += f.x * m.x + f.y * m.y + f.z * m.z + f.w * m.w;
        }
        s = wave_red(s); tt = wave_red(tt); sf = wave_red(sf); dp = wave_red(dp);
        if (lane == 0) {
            kl_acc += (float)C_N * (tt / s) - sf;
            float dot = dp * (1.f / (float)B_N);  // (F mu)_b, mu = colsum/B
            fmu_acc += dot * dot;
        }
    }
    __shared__ float sm[4][2];
    if (lane == 0) { sm[wid][0] = kl_acc; sm[wid][1] = fmu_acc; }
    __syncthreads();
    if (threadIdx.x == 0) {
        atomicAdd(&acc[A_KL],   sm[0][0] + sm[1][0] + sm[2][0] + sm[3][0]);
        atomicAdd(&acc[A_FMU2], sm[0][1] + sm[1][1] + sm[2][1] + sm[3][1]);
    }
}

// ---------------- bf16 Gram: S += X X^T over triangular tiles, K-split, atomic epilogue ----------------
// X: [Mp][K] bf16 row-major.  128x128 tile per block, 4 waves (2x2 of 64x64), BK=32, 16x16x32 MFMA.
__global__ __launch_bounds__(256) void gram_kernel(const short* __restrict__ X,
                                                   float* __restrict__ S,
                                                   int Mp, int K, int T, int ntri, int chunkK) {
    __shared__ __align__(16) short At[128 * 32];
    __shared__ __align__(16) short Bt[128 * 32];
    int tid = threadIdx.x;
    int tile = blockIdx.x % ntri;
    int kc   = blockIdx.x / ntri;
    int bi = 0, rem = tile;
    while (rem >= T - bi) { rem -= T - bi; bi++; }
    int bj = bi + rem;
    int i0 = bi * 128, j0 = bj * 128;
    int k0 = kc * chunkK;
    bool same = (bi == bj);

    int wave = tid >> 6, lane = tid & 63;
    int wm = wave >> 1, wn = wave & 1;
    int quad = lane >> 4, l16 = lane & 15;

    f32x4 acc[4][4];
#pragma unroll
    for (int i = 0; i < 4; i++)
#pragma unroll
        for (int j = 0; j < 4; j++) acc[i][j] = { 0.f, 0.f, 0.f, 0.f };

    for (int kk = 0; kk < chunkK; kk += 32) {
        int kcur = k0 + kk;
#pragma unroll
        for (int it = 0; it < 2; it++) {   // stage A tile (128x32), 16B per lane, wave-uniform base + lane*16
            int g = it * 256 + tid;
            int row = g >> 2, koff = (g & 3) * 8;
            const short* gp = X + (size_t)(i0 + row) * K + kcur + koff;
            __builtin_amdgcn_global_load_lds((const __attribute__((address_space(1))) unsigned int*)gp,
                                             (__attribute__((address_space(3))) unsigned int*)(At + g * 8),
                                             16, 0, 0);
        }
        if (!same) {
#pragma unroll
            for (int it = 0; it < 2; it++) {
                int g = it * 256 + tid;
                int row = g >> 2, koff = (g & 3) * 8;
                const short* gp = X + (size_t)(j0 + row) * K + kcur + koff;
                __builtin_amdgcn_global_load_lds((const __attribute__((address_space(1))) unsigned int*)gp,
                                                 (__attribute__((address_space(3))) unsigned int*)(Bt + g * 8),
                                                 16, 0, 0);
            }
        }
        __syncthreads();
        const short* Bsrc = same ? At : Bt;
        s16x8 af[4], bf[4];
#pragma unroll
        for (int f = 0; f < 4; f++) {
            int mrow = wm * 64 + f * 16 + l16;
            af[f] = *(const s16x8*)(At + mrow * 32 + quad * 8);
            int nrow = wn * 64 + f * 16 + l16;
            bf[f] = *(const s16x8*)(Bsrc + nrow * 32 + quad * 8);
        }
#pragma unroll
        for (int i = 0; i < 4; i++)
#pragma unroll
            for (int j = 0; j < 4; j++)
                acc[i][j] = __builtin_amdgcn_mfma_f32_16x16x32_bf16(af[i], bf[j], acc[i][j], 0, 0, 0);
        __syncthreads();
    }

#pragma unroll
    for (int i = 0; i < 4; i++)
#pragma unroll
        for (int j = 0; j < 4; j++)
#pragma unroll
            for (int r = 0; r < 4; r++) {
                int grow = i0 + wm * 64 + i * 16 + quad * 4 + r;
                int gcol = j0 + wn * 64 + j * 16 + l16;
                atomicAdd(&S[(size_t)grow * Mp + gcol], acc[i][j][r]);
            }
}

// ---------------- Frobenius^2 over computed triangular tiles (off-diag weighted 2x) ----------------
__global__ __launch_bounds__(256) void fro_reduce_kernel(const float* __restrict__ S,
                                                         int Mp, int T, float* __restrict__ slot) {
    int tile = blockIdx.x;
    int bi = 0, rem = tile;
    while (rem >= T - bi) { rem -= T - bi; bi++; }
    int bj = bi + rem;
    size_t base = (size_t)bi * 128 * Mp + (size_t)bj * 128;
    float sum = 0.f;
    for (int l = threadIdx.x * 4; l < 128 * 128; l += 1024) {
        int row = l >> 7, col = l & 127;
        float4 v = *(const float4*)(S + base + (size_t)row * Mp + col);
        sum += v.x * v.x + v.y * v.y + v.z * v.z + v.w * v.w;
    }
    sum = wave_red(sum);
    __shared__ float sm[4];
    int wid = threadIdx.x >> 6, lane = threadIdx.x & 63;
    if (lane == 0) sm[wid] = sum;
    __syncthreads();
    if (threadIdx.x == 0) {
        float w = (bi == bj) ? 1.f : 2.f;
        atomicAdd(slot, w * (sm[0] + sm[1] + sm[2] + sm[3]));
    }
}

// ---------------- final combine ----------------
__global__ __launch_bounds__(256) void final_kernel(const float* __restrict__ acc,
                                                    const float* __restrict__ colsum,
                                                    float* __restrict__ out) {
    float s = 0.f;
    for (int c = threadIdx.x; c < C_N; c += 256) { float v = colsum[c]; s += v * v; }
    s = wave_red(s);
    __shared__ float sm[4];
    int wid = threadIdx.x >> 6, lane = threadIdx.x & 63;
    if (lane == 0) sm[wid] = s;
    __syncthreads();
    if (threadIdx.x == 0) {
        double musq_raw = (double)(sm[0] + sm[1] + sm[2] + sm[3]);   // sum colsum^2 = B^2 * ||mu||^2
        double Bd = (double)B_N;
        double nll = -((double)acc[A_NLL] / Bd);
        double kl  = (double)acc[A_KL] / Bd;
        double trG = (double)acc[A_SUMSQF];
        double musq = musq_raw / (Bd * Bd);
        double cov = (double)acc[A_GFRO] / (Bd * Bd)
                   - (2.0 / Bd) * (double)acc[A_FMU2]
                   + musq * musq
                   - 2.0 * (trG / Bd - musq)
                   + (double)C_N;
        double ortho = (double)acc[A_HFRO] - 2.0 * (double)acc[A_L2SQ] + (double)NCLS_N;
        double loss = 1.0 * nll + 0.2 * kl + 0.2 * cov + 0.1 * ortho
                    + 0.1 * (double)acc[A_L1] + 0.1 * sqrt((double)acc[A_L2SQ]);
        out[0] = (float)loss;
    }
}

extern "C" void kernel_launch(void* const* d_in, const int* in_sizes, int n_in,
                              void* d_out, int out_size, void* d_ws, size_t ws_size,
                              hipStream_t stream) {
    (void)in_sizes; (void)n_in; (void)out_size; (void)ws_size;
    const float* output_lp = (const float*)d_in[0];
    const int*   target    = (const int*)d_in[1];
    const float* W         = (const float*)d_in[2];
    const float* F         = (const float*)d_in[3];

    char*  ws     = (char*)d_ws;
    float* acc    = (float*)(ws + ACC_OFF);
    float* colsum = (float*)(ws + COLSUM_OFF);
    short* Fbt    = (short*)(ws + FBT_OFF);
    short* Wb     = (short*)(ws + WB_OFF);
    float* G      = (float*)(ws + G_OFF);
    float* H      = (float*)(ws + H_OFF);

    // zero accumulators + atomic targets (ws is poisoned 0xAA before every launch)
    hipMemsetAsync(ws, 0, 8192, stream);
    hipMemsetAsync(G, 0, (size_t)C_N * C_N * 4, stream);
    hipMemsetAsync(H, 0, (size_t)1024 * 1024 * 4, stream);

    nll_kernel<<<B_N / 256, 256, 0, stream>>>(output_lp, target, acc);
    wpass_kernel<<<(1024 * C_N / 4) / 256, 256, 0, stream>>>(W, Wb, acc);
    fpass_kernel<<<dim3(C_N / 256, B_N / 128), 256, 0, stream>>>(F, Fbt, colsum, acc);
    klpass_kernel<<<1024, 256, 0, stream>>>(F, colsum, acc);

    // G = Fbt Fbt^T : Mp=1280, K=16384, T=10, ntri=55, ksplit=8 (chunk 2048) -> 440 blocks
    gram_kernel<<<55 * 8, 256, 0, stream>>>(Fbt, G, C_N, B_N, 10, 55, 2048);
    // H = Wb Wb^T : Mp=1024, K=1280, T=8, ntri=36, ksplit=4 (chunk 320) -> 144 blocks
    gram_kernel<<<36 * 4, 256, 0, stream>>>(Wb, H, 1024, C_N, 8, 36, 320);

    fro_reduce_kernel<<<55, 256, 0, stream>>>(G, C_N, 10, acc + A_GFRO);
    fro_reduce_kernel<<<36, 256, 0, stream>>>(H, 1024, 8, acc + A_HFRO);

    final_kernel<<<1, 256, 0, stream>>>(acc, colsum, (float*)d_out);
}